// Round 1
// baseline (4644.041 us; speedup 1.0000x reference)
//
#include <hip/hip_runtime.h>

#define N_ROWS   131072
#define KCODES   128
#define DIM      510
#define DC       32          // d-chunk per LDS stage
#define RSTRIDE  36          // DC + 4 pad (144 B rows, 16B-aligned, lane-stride hits distinct bank quads)
#define BROWS    128         // rows per block
#define NCHUNK   16          // ceil(510/32)
#define BUFSZ    (BROWS * RSTRIDE)

// c_sq in fp64 (per-code errors shift dist per-code and can flip argmin; make them ~0)
__global__ __launch_bounds__(64) void csq_kernel(const float* __restrict__ cb,
                                                 float* __restrict__ csq) {
    int k = blockIdx.x;
    int l = threadIdx.x;
    double s = 0.0;
    for (int d = l; d < DIM; d += 64) {
        double v = (double)cb[k * DIM + d];
        s += v * v;
    }
    for (int m = 32; m > 0; m >>= 1) s += __shfl_down(s, m);
    if (l == 0) csq[k] = (float)s;
}

// T14 async-stage split + double-buffered LDS:
//   per chunk: issue next chunk's global loads (float2, 8B-aligned always) into regs,
//   compute current chunk from LDS, ds_write the prefetched regs to the other buffer,
//   ONE barrier per chunk. Arithmetic (fma chain order, dist rounding, tie-break) is
//   bit-identical to the previous passing kernel — only data movement changed.
__global__ __launch_bounds__(256, 2) void vq_kernel(const float* __restrict__ z,
                                                    const float* __restrict__ cb,
                                                    const float* __restrict__ csq,
                                                    float* __restrict__ out) {
    __shared__ __align__(16) float zs[2][BUFSZ];
    __shared__ __align__(16) float cs[2][BUFSZ];
    __shared__ int kbest[BROWS];

    const int tid  = threadIdx.x;
    const int wave = tid >> 6;           // 0..3
    const int lane = tid & 63;
    const int lr   = lane >> 3;          // 0..7  (row group within wave)
    const int lc   = lane & 7;           // 0..7  (code group within wave)
    const long rowBase = (long)blockIdx.x * BROWS;

    // rows of this thread:  wave*32 + lr + 8*i   (i = 0..3)
    // codes of this thread: lc + 8*j             (j = 0..15, ascending k for tie-break)
    const int rbase = wave * 32 + lr;

    // staging decomposition: thread owns float2-pair sp of rows (sr + 16*t), t = 0..7
    // (16 lanes per row -> 128 B contiguous per 16 lanes: coalesced)
    const int sr = tid >> 4;             // 0..15
    const int sp = tid & 15;             // 0..15
    const float2* __restrict__ z2 = (const float2*)z;
    const float2* __restrict__ c2 = (const float2*)cb;
    const long zsb    = (rowBase + sr) * (DIM / 2) + sp;
    const int  csb    = sr * (DIM / 2) + sp;
    const int  ldsoff = sr * RSTRIDE + 2 * sp;     // float2 write target (8B aligned)

    float acc[4][16];
    float zsq[4];
#pragma unroll
    for (int i = 0; i < 4; ++i) {
        zsq[i] = 0.f;
#pragma unroll
        for (int j = 0; j < 16; ++j) acc[i][j] = 0.f;
    }

    // prologue: stage chunk 0 into buffer 0 (no guard needed: d <= 31 < 510)
#pragma unroll
    for (int t = 0; t < 8; ++t) {
        float2 vz = z2[zsb + (long)(t * 16 * (DIM / 2))];
        float2 vc = c2[csb + t * 16 * (DIM / 2)];
        *(float2*)&zs[0][ldsoff + t * 16 * RSTRIDE] = vz;
        *(float2*)&cs[0][ldsoff + t * 16 * RSTRIDE] = vc;
    }
    __syncthreads();

    for (int ch = 0; ch < NCHUNK; ++ch) {
        const int b = ch & 1;

        // ---- issue-early: prefetch chunk ch+1 into registers ----
        // chunk 15 covers d = 480..509; pair sp==15 (d = 510,511) is out of range
        // (and for the last row/code would read past the buffer) -> zero-fill.
        float2 pz[8], pc[8];
        const bool pref = (ch + 1 < NCHUNK);
        if (pref) {
            const int dh = (ch + 1) * (DC / 2);
            if ((ch + 1 == NCHUNK - 1) && (sp == 15)) {
#pragma unroll
                for (int t = 0; t < 8; ++t) {
                    pz[t] = make_float2(0.f, 0.f);
                    pc[t] = make_float2(0.f, 0.f);
                }
            } else {
#pragma unroll
                for (int t = 0; t < 8; ++t) {
                    pz[t] = z2[zsb + (long)(t * 16 * (DIM / 2) + dh)];
                    pc[t] = c2[csb + t * 16 * (DIM / 2) + dh];
                }
            }
        }

        // ---- compute current chunk from LDS (identical arithmetic) ----
        const float* zbuf = zs[b];
        const float* cbuf = cs[b];
#pragma unroll
        for (int dd = 0; dd < DC; dd += 4) {
            float4 zv[4];
#pragma unroll
            for (int i = 0; i < 4; ++i)
                zv[i] = *(const float4*)&zbuf[(rbase + 8 * i) * RSTRIDE + dd];
            // z_sq accumulated with the same chain structure as the dots
#pragma unroll
            for (int i = 0; i < 4; ++i) {
                zsq[i] = fmaf(zv[i].x, zv[i].x, zsq[i]);
                zsq[i] = fmaf(zv[i].y, zv[i].y, zsq[i]);
                zsq[i] = fmaf(zv[i].z, zv[i].z, zsq[i]);
                zsq[i] = fmaf(zv[i].w, zv[i].w, zsq[i]);
            }
#pragma unroll
            for (int j = 0; j < 16; ++j) {
                float4 cv = *(const float4*)&cbuf[(lc + 8 * j) * RSTRIDE + dd];
#pragma unroll
                for (int i = 0; i < 4; ++i) {
                    acc[i][j] = fmaf(zv[i].x, cv.x, acc[i][j]);
                    acc[i][j] = fmaf(zv[i].y, cv.y, acc[i][j]);
                    acc[i][j] = fmaf(zv[i].z, cv.z, acc[i][j]);
                    acc[i][j] = fmaf(zv[i].w, cv.w, acc[i][j]);
                }
            }
        }

        // ---- write-late: prefetched regs -> other buffer (safe: that buffer was
        // last READ in iteration ch-1, whose end-barrier has passed) ----
        if (pref) {
            float* zd = zs[b ^ 1];
            float* cd = cs[b ^ 1];
#pragma unroll
            for (int t = 0; t < 8; ++t) {
                *(float2*)&zd[ldsoff + t * 16 * RSTRIDE] = pz[t];
                *(float2*)&cd[ldsoff + t * 16 * RSTRIDE] = pc[t];
            }
        }
        __syncthreads();   // single barrier per chunk (drains vmcnt+lgkm once)
    }

    // argmin epilogue — replicate np's rounding sequence:
    //   t = fp32(z_sq - 2*dot)  (2*dot exact);  dist = fp32(t + c_sq)
#pragma unroll
    for (int i = 0; i < 4; ++i) {
        float bd = 3.0e38f;
        int   bk = 0;
#pragma unroll
        for (int j = 0; j < 16; ++j) {
            int k = lc + 8 * j;
            float t    = zsq[i] - 2.0f * acc[i][j];
            float dist = t + csq[k];
            if (dist < bd) { bd = dist; bk = k; }   // strict <: first (lowest k) wins
        }
#pragma unroll
        for (int m = 1; m < 8; m <<= 1) {
            float od = __shfl_xor(bd, m);
            int   ok = __shfl_xor(bk, m);
            if (od < bd || (od == bd && ok < bk)) { bd = od; bk = ok; }
        }
        if (lc == 0) kbest[rbase + 8 * i] = bk;
    }
    __syncthreads();

    // gather: copy winning codebook rows to out (float2, rows are 8B-aligned)
    for (int r = wave; r < BROWS; r += 4) {
        int k = kbest[r];
        const float2* src = (const float2*)(cb + (long)k * DIM);
        float2* dst = (float2*)(out + (rowBase + r) * DIM);
        for (int d2 = lane; d2 < DIM / 2; d2 += 64) dst[d2] = src[d2];
    }
}

extern "C" void kernel_launch(void* const* d_in, const int* in_sizes, int n_in,
                              void* d_out, int out_size, void* d_ws, size_t ws_size,
                              hipStream_t stream) {
    const float* z  = (const float*)d_in[0];
    const float* cb = (const float*)d_in[1];
    float* out = (float*)d_out;
    float* csq = (float*)d_ws;   // 128 floats of scratch

    csq_kernel<<<KCODES, 64, 0, stream>>>(cb, csq);
    vq_kernel<<<N_ROWS / BROWS, 256, 0, stream>>>(z, cb, csq, out);
}

// Round 2
// 857.547 us; speedup vs baseline: 5.4155x; 5.4155x over previous
//
#include <hip/hip_runtime.h>

#define N_ROWS   131072
#define KCODES   128
#define DIM      510
#define DC       32          // d-chunk per LDS stage
#define BROWS    128         // rows per block
#define NCHUNK   16          // ceil(510/32)
#define BUFSZ    (BROWS * DC)   // 4096 floats per chunk buffer

// c_sq in fp64 (per-code errors shift dist per-code and can flip argmin; make them ~0)
// Also zero-fills the 32-float zero-pad region used as DMA source for the d>=510 tail.
__global__ __launch_bounds__(64) void csq_kernel(const float* __restrict__ cb,
                                                 float* __restrict__ csq,
                                                 float* __restrict__ zpad) {
    int k = blockIdx.x;
    int l = threadIdx.x;
    if (k == 0 && l < 32) zpad[l] = 0.f;
    double s = 0.0;
    for (int d = l; d < DIM; d += 64) {
        double v = (double)cb[k * DIM + d];
        s += v * v;
    }
    for (int m = 32; m > 0; m >>= 1) s += __shfl_down(s, m);
    if (l == 0) csq[k] = (float)s;
}

// global->LDS DMA staging of one chunk (z + cb) into linear, XOR-swizzled buffers.
// Layout: element (row r, dim d) of the chunk lives at dword  r*32 + (d ^ 4*(r&7)).
// DMA writes linearly (wave-uniform LDS base + lane*4B), so the SOURCE address is
// inverse-swizzled per lane (rule 21: linear dest + swizzled source + swizzled read).
// Segment q of wave w covers LDS dwords F = (w*16+q)*64 + lane:
//   r = 32w + 2q + (lane>>5),  d' = lane&31,  true d = d' ^ 4*(r&7).
template <bool GUARD>
__device__ __forceinline__ void stage_chunk(const float* __restrict__ z,
                                            const float* __restrict__ cb,
                                            const float* __restrict__ zpad,
                                            float* zbuf, float* cbuf,
                                            long rowBase, int d0,
                                            int wave, int hl, int dl) {
#pragma unroll
    for (int q = 0; q < 16; ++q) {
        const int r  = 32 * wave + 2 * q + hl;
        const int dq = dl ^ (4 * ((2 * q + hl) & 7));
        const int gd = d0 + dq;
        const float* srcz = z + (rowBase + r) * (long)DIM + gd;
        const float* srcc = cb + r * DIM + gd;
        if (GUARD && gd >= DIM) {      // tail chunk: d = 510/511 -> zeros (per-lane select)
            srcz = zpad + dl;
            srcc = zpad + dl;
        }
        float* dstz = zbuf + (wave * 16 + q) * 64;   // wave-uniform base
        float* dstc = cbuf + (wave * 16 + q) * 64;
        __builtin_amdgcn_global_load_lds(
            (const __attribute__((address_space(1))) void*)srcz,
            (__attribute__((address_space(3))) void*)dstz, 4, 0, 0);
        __builtin_amdgcn_global_load_lds(
            (const __attribute__((address_space(1))) void*)srcc,
            (__attribute__((address_space(3))) void*)dstc, 4, 0, 0);
    }
}

__global__ __launch_bounds__(256, 2) void vq_kernel(const float* __restrict__ z,
                                                    const float* __restrict__ cb,
                                                    const float* __restrict__ csq,
                                                    const float* __restrict__ zpad,
                                                    float* __restrict__ out) {
    __shared__ __align__(16) float zs[2][BUFSZ];
    __shared__ __align__(16) float cs[2][BUFSZ];
    __shared__ int kbest[BROWS];

    const int tid  = threadIdx.x;
    const int wave = tid >> 6;           // 0..3
    const int lane = tid & 63;
    const int lr   = lane >> 3;          // 0..7  (row group within wave)
    const int lc   = lane & 7;           // 0..7  (code group within wave)
    const int hl   = lane >> 5;          // staging: half-of-wave
    const int dl   = lane & 31;          // staging: dword-in-segment
    const long rowBase = (long)blockIdx.x * BROWS;

    // rows of this thread:  wave*32 + lr + 8*i   (i = 0..3)
    // codes of this thread: lc + 8*j             (j = 0..15, ascending k for tie-break)
    const int rbase = wave * 32 + lr;
    const int zsw   = 4 * lr;            // read-side swizzle (r&7 == lr for z rows)
    const int csw   = 4 * lc;            // read-side swizzle (r&7 == lc for cs rows)

    float acc[4][16];
    float zsq[4];
#pragma unroll
    for (int i = 0; i < 4; ++i) {
        zsq[i] = 0.f;
#pragma unroll
        for (int j = 0; j < 16; ++j) acc[i][j] = 0.f;
    }

    // prologue: DMA chunk 0 into buffer 0
    stage_chunk<false>(z, cb, zpad, zs[0], cs[0], rowBase, 0, wave, hl, dl);
    __syncthreads();   // drains vmcnt -> chunk 0 resident

    for (int ch = 0; ch < NCHUNK; ++ch) {
        const int b = ch & 1;

        // issue-early: DMA chunk ch+1 into the other buffer (no registers held;
        // latency hides under this chunk's compute; drained by the end barrier)
        if (ch + 1 < NCHUNK) {
            if (ch + 1 == NCHUNK - 1)
                stage_chunk<true >(z, cb, zpad, zs[b ^ 1], cs[b ^ 1], rowBase,
                                   (ch + 1) * DC, wave, hl, dl);
            else
                stage_chunk<false>(z, cb, zpad, zs[b ^ 1], cs[b ^ 1], rowBase,
                                   (ch + 1) * DC, wave, hl, dl);
        }

        // compute current chunk from LDS (arithmetic identical to the passing kernel;
        // only the address swizzle differs, and a swizzled float4 still returns
        // elements d = dd..dd+3 in order)
        const float* zbuf = zs[b];
        const float* cbuf = cs[b];
#pragma unroll
        for (int dd = 0; dd < DC; dd += 4) {
            float4 zv[4];
#pragma unroll
            for (int i = 0; i < 4; ++i)
                zv[i] = *(const float4*)&zbuf[(rbase + 8 * i) * DC + (dd ^ zsw)];
            // z_sq accumulated with the same chain structure as the dots
#pragma unroll
            for (int i = 0; i < 4; ++i) {
                zsq[i] = fmaf(zv[i].x, zv[i].x, zsq[i]);
                zsq[i] = fmaf(zv[i].y, zv[i].y, zsq[i]);
                zsq[i] = fmaf(zv[i].z, zv[i].z, zsq[i]);
                zsq[i] = fmaf(zv[i].w, zv[i].w, zsq[i]);
            }
#pragma unroll
            for (int j = 0; j < 16; ++j) {
                float4 cv = *(const float4*)&cbuf[(lc + 8 * j) * DC + (dd ^ csw)];
#pragma unroll
                for (int i = 0; i < 4; ++i) {
                    acc[i][j] = fmaf(zv[i].x, cv.x, acc[i][j]);
                    acc[i][j] = fmaf(zv[i].y, cv.y, acc[i][j]);
                    acc[i][j] = fmaf(zv[i].z, cv.z, acc[i][j]);
                    acc[i][j] = fmaf(zv[i].w, cv.w, acc[i][j]);
                }
            }
        }

        __syncthreads();   // single barrier per chunk: drains DMA + releases buffers
    }

    // argmin epilogue — replicate np's rounding sequence:
    //   t = fp32(z_sq - 2*dot)  (2*dot exact);  dist = fp32(t + c_sq)
#pragma unroll
    for (int i = 0; i < 4; ++i) {
        float bd = 3.0e38f;
        int   bk = 0;
#pragma unroll
        for (int j = 0; j < 16; ++j) {
            int k = lc + 8 * j;
            float t    = zsq[i] - 2.0f * acc[i][j];
            float dist = t + csq[k];
            if (dist < bd) { bd = dist; bk = k; }   // strict <: first (lowest k) wins
        }
#pragma unroll
        for (int m = 1; m < 8; m <<= 1) {
            float od = __shfl_xor(bd, m);
            int   ok = __shfl_xor(bk, m);
            if (od < bd || (od == bd && ok < bk)) { bd = od; bk = ok; }
        }
        if (lc == 0) kbest[rbase + 8 * i] = bk;
    }
    __syncthreads();

    // gather: copy winning codebook rows to out (float2, rows are 8B-aligned)
    for (int r = wave; r < BROWS; r += 4) {
        int k = kbest[r];
        const float2* src = (const float2*)(cb + (long)k * DIM);
        float2* dst = (float2*)(out + (rowBase + r) * DIM);
        for (int d2 = lane; d2 < DIM / 2; d2 += 64) dst[d2] = src[d2];
    }
}

extern "C" void kernel_launch(void* const* d_in, const int* in_sizes, int n_in,
                              void* d_out, int out_size, void* d_ws, size_t ws_size,
                              hipStream_t stream) {
    const float* z  = (const float*)d_in[0];
    const float* cb = (const float*)d_in[1];
    float* out  = (float*)d_out;
    float* csq  = (float*)d_ws;             // 128 floats
    float* zpad = (float*)d_ws + KCODES;    // 32 zero floats (DMA tail source)

    csq_kernel<<<KCODES, 64, 0, stream>>>(cb, csq, zpad);
    vq_kernel<<<N_ROWS / BROWS, 256, 0, stream>>>(z, cb, csq, zpad, out);
}